// Round 10
// baseline (264.460 us; speedup 1.0000x reference)
//
#include <hip/hip_runtime.h>

#define B_SZ 1024
#define D_SZ 128
#define KTERMS 7
#define QPAD 36   // floats per quarter-segment: 32 data + 4 pad -> conflict-free quarters

typedef float vfloat4 __attribute__((ext_vector_type(4)));

__device__ inline float bflo(unsigned u) { return __uint_as_float(u << 16); }
__device__ inline float bfhi(unsigned u) { return __uint_as_float(u & 0xffff0000u); }

// dual 32-elem dot sharing ONE vector read: (A-quarter-row . v) and (W-quarter-row . v)
__device__ inline void dot32x2(const unsigned* ra, const unsigned* rw,
                               const float* v, float& oa, float& ow) {
    float a0=0.f,a1=0.f,a2=0.f,a3=0.f, w0=0.f,w1=0.f,w2=0.f,w3=0.f;
#pragma unroll
    for (int j = 0; j < 8; ++j) {
        vfloat4 vv = *(const vfloat4*)(v + 4 * j);
        a0 = fmaf(bflo(ra[2*j]),   vv.x, a0);
        a1 = fmaf(bfhi(ra[2*j]),   vv.y, a1);
        a2 = fmaf(bflo(ra[2*j+1]), vv.z, a2);
        a3 = fmaf(bfhi(ra[2*j+1]), vv.w, a3);
        w0 = fmaf(bflo(rw[2*j]),   vv.x, w0);
        w1 = fmaf(bfhi(rw[2*j]),   vv.y, w1);
        w2 = fmaf(bflo(rw[2*j+1]), vv.z, w2);
        w3 = fmaf(bfhi(rw[2*j+1]), vv.w, w3);
    }
    oa = (a0 + a1) + (a2 + a3);
    ow = (w0 + w1) + (w2 + w3);
}

// single 32-elem dot (round B: different vectors for A and W)
__device__ inline float dot32(const unsigned* rq, const float* v) {
    float a0=0.f,a1=0.f,a2=0.f,a3=0.f;
#pragma unroll
    for (int j = 0; j < 8; ++j) {
        vfloat4 vv = *(const vfloat4*)(v + 4 * j);
        a0 = fmaf(bflo(rq[2*j]),   vv.x, a0);
        a1 = fmaf(bfhi(rq[2*j]),   vv.y, a1);
        a2 = fmaf(bflo(rq[2*j+1]), vv.z, a2);
        a3 = fmaf(bfhi(rq[2*j+1]), vv.w, a3);
    }
    return (a0 + a1) + (a2 + a3);
}

// One block (512 threads) per batch.  Both jobs fused, each with its own mapping:
//   P2: quarter-row loads (cache-served second read)  [issued first - no store dep]
//   P1: coalesced stream A0,W -> nontemporal A1,A2    [writes stay clean 131MB]
//   P3: Taylor chain; matrix bf16 in regs; update fused in-register
//       (every thread holds full u1..u4 of its row after shfl butterflies).
// LDS ~1.7KB, VGPR ~70 -> 4 blocks/CU; staggered retirement overlaps gen g+1's
// streaming with gen g's chains without any dispatch-order assumption (r9 lesson).
__global__ void __launch_bounds__(512, 4)
magnus_kernel(const float* __restrict__ t0p, const float* __restrict__ hp,
              const float* __restrict__ y0, const float* __restrict__ A0,
              const float* __restrict__ W, float* __restrict__ out)
{
    __shared__ __align__(16) float svr [4 * QPAD];
    __shared__ __align__(16) float su1r[4 * QPAD];
    __shared__ __align__(16) float su2r[4 * QPAD];

    const int b   = blockIdx.x;
    const int tid = threadIdx.x;
    const int row = tid >> 2;     // 0..127
    const int q   = tid & 3;      // quarter 0..3
    const float h  = hp[0];
    const float tb = t0p[b];
    const float SQ3_6 = 0.28867513459481287f;  // sqrt(3)/6
    const float t1 = tb + (0.5f - SQ3_6) * h;
    const float t2 = tb + (0.5f + SQ3_6) * h;

    const size_t moff = (size_t)b * (D_SZ * D_SZ);

    // ---- P2 loads FIRST (program order): chain data never waits on stores ----
    const int fbase = row * 32 + q * 8;   // float4 index of thread's 128B chunk
    const float4* Ap = (const float4*)(A0 + moff) + fbase;
    const float4* Wp = (const float4*)(W + moff) + fbase;
    float4 ta[8], tw[8];
#pragma unroll
    for (int it = 0; it < 8; ++it) { ta[it] = Ap[it]; tw[it] = Wp[it]; }
    float yv = y0[(size_t)b * D_SZ + row];   // y0 row (4-lane broadcast read)

    // ---- P1: coalesced stream; nontemporal stores ----
    {
        const float4* A0v = (const float4*)(A0 + moff);
        const float4* Wv  = (const float4*)(W + moff);
        vfloat4* o1 = (vfloat4*)(out + (size_t)B_SZ * D_SZ + moff);
        vfloat4* o2 = (vfloat4*)(out + (size_t)B_SZ * D_SZ
                                     + (size_t)B_SZ * D_SZ * D_SZ + moff);
#pragma unroll 8
        for (int it = 0; it < 8; ++it) {
            int i = it * 512 + tid;
            float4 a = A0v[i];
            float4 w = Wv[i];
            vfloat4 p1, p2;
            p1.x = fmaf(t1, w.x, a.x); p1.y = fmaf(t1, w.y, a.y);
            p1.z = fmaf(t1, w.z, a.z); p1.w = fmaf(t1, w.w, a.w);
            p2.x = fmaf(t2, w.x, a.x); p2.y = fmaf(t2, w.y, a.y);
            p2.z = fmaf(t2, w.z, a.z); p2.w = fmaf(t2, w.w, a.w);
            __builtin_nontemporal_store(p1, o1 + i);
            __builtin_nontemporal_store(p2, o2 + i);
        }
    }

    // ---- pack quarter-rows to bf16 regs (cvt asm output: not rematerializable) ----
    unsigned ra[16], rw[16];
#pragma unroll
    for (int it = 0; it < 8; ++it) {
        asm("v_cvt_pk_bf16_f32 %0, %1, %2" : "=v"(ra[2*it])   : "v"(ta[it].x), "v"(ta[it].y));
        asm("v_cvt_pk_bf16_f32 %0, %1, %2" : "=v"(ra[2*it+1]) : "v"(ta[it].z), "v"(ta[it].w));
        asm("v_cvt_pk_bf16_f32 %0, %1, %2" : "=v"(rw[2*it])   : "v"(tw[it].x), "v"(tw[it].y));
        asm("v_cvt_pk_bf16_f32 %0, %1, %2" : "=v"(rw[2*it+1]) : "v"(tw[it].z), "v"(tw[it].w));
    }

    // ---- P3 init ----
    float yacc = yv;                       // only q==0's copy is used at the end
    if (tid < D_SZ) {
        svr[(tid >> 5) * QPAD + (tid & 31)] = y0[(size_t)b * D_SZ + tid];
    }
    __syncthreads();

    const float hs = h * (tb + 0.5f * h);           // h * s
    const float c3 = h * h * h * (1.0f / 12.0f);    // h^3 / 12
    const int uflat = (row >> 5) * QPAD + (row & 31);
    // KTERMS=7: ||Omega|| <~ 0.4 -> truncation ~1e-7, invisible vs bf16 noise.

#pragma unroll
    for (int k = 1; k <= KTERMS; ++k) {
        // Round A: u1 = A0 v, u2 = W v  (one shared v-read)
        float pa, pw;
        dot32x2(ra, rw, svr + q * QPAD, pa, pw);
        pa += __shfl_xor(pa, 1); pa += __shfl_xor(pa, 2);
        pw += __shfl_xor(pw, 1); pw += __shfl_xor(pw, 2);
        if (q == 0) { su1r[uflat] = pa; su2r[uflat] = pw; }
        __syncthreads();
        // Round B: u3 = A0 u2, u4 = W u1
        float pb = dot32(ra, su2r + q * QPAD);
        float pc = dot32(rw, su1r + q * QPAD);
        pb += __shfl_xor(pb, 1); pb += __shfl_xor(pb, 2);
        pc += __shfl_xor(pc, 1); pc += __shfl_xor(pc, 2);
        // fused update: every thread has full u1..u4 of its row in regs
        float wn = (h * pa + hs * pw - c3 * (pb - pc)) * (1.0f / (float)k);
        yacc += wn;
        if (k < KTERMS) {
            if (q == 0) svr[uflat] = wn;
            __syncthreads();
        }
    }

    if (q == 0) {
        out[(size_t)b * D_SZ + row] = yacc;
    }
}

extern "C" void kernel_launch(void* const* d_in, const int* in_sizes, int n_in,
                              void* d_out, int out_size, void* d_ws, size_t ws_size,
                              hipStream_t stream) {
    const float* t0 = (const float*)d_in[0];
    const float* h  = (const float*)d_in[1];
    const float* y0 = (const float*)d_in[2];
    const float* A0 = (const float*)d_in[3];
    const float* W  = (const float*)d_in[4];
    float* out = (float*)d_out;
    magnus_kernel<<<B_SZ, 512, 0, stream>>>(t0, h, y0, A0, W, out);
}